// Round 8
// baseline (261.857 us; speedup 1.0000x reference)
//
#include <hip/hip_runtime.h>

// Seq2SeqLSTM: H=64, F=8, T=512, P=64, B=1024, fp32 in/out.
// R8: P-chain (x-contribution MFMAs) issues INSIDE the post-barrier ds_read
// latency window (depends only on immutable xs), not after the cell update.
// Two P register sets decouple consecutive steps. Q-chain issue order g,i,f,o
// so the transcendental chain starts ASAP. Otherwise R7 structure:
// MB=4 over 256 blocks; lane (q,col) owns cell (batch q, unit wv*16+col);
// batch b at A-row 4b so C/D row=4q+0 puts the lane's gates in acc[.][0];
// fp16 weights/h/x, weights pre-scaled by log2e (2*log2e for g-gate).

#define Hh 64
#define Ff 8
#define Tt 512
#define Pp 64
#define BATCH 1024
#define MB 4
#define NBLK (BATCH / MB)   // 256 blocks
#define ROWS 72             // halves per A row (64 + 8 pad)
#define ABUF (16 * ROWS + 64)
#define XSTRIDE 32          // halves per x step-row: 4 batches * 8

typedef __attribute__((ext_vector_type(8))) _Float16 half8;
typedef __attribute__((ext_vector_type(4))) _Float16 half4;
typedef __attribute__((ext_vector_type(4))) float f32x4;

#define LOG2E  1.44269504088896340736f
#define K2LOG2 2.88538008177792681472f   // 2*log2e

__device__ __forceinline__ float sig_pre(float a) {   // a pre-scaled by log2e
    return __builtin_amdgcn_rcpf(1.f + __builtin_amdgcn_exp2f(-a));
}
__device__ __forceinline__ float tanh_pre(float a) {  // a pre-scaled by 2*log2e
    return 1.f - 2.f * __builtin_amdgcn_rcpf(1.f + __builtin_amdgcn_exp2f(a));
}
// A-row swizzle (halves): rows 4b (writers) keep offset 0.
__device__ __forceinline__ int arow_base(int m) { return m * ROWS + (m & 3) * 16; }

// B-fragments: 4 gate tiles, fp16, log2e-pre-scaled (2*log2e for g-gate).
// B layout (16x16x32): lane holds B[k = kc*32 + q*8 + j][n = col].
__device__ __forceinline__ void load_wfrags(
    const float* __restrict__ Whh, const float* __restrict__ Wih,
    int wv, int q, int col, half8 w0[4], half8 w1[4], half8 wx[4])
{
    #pragma unroll
    for (int Tg = 0; Tg < 4; ++Tg) {
        int g = Tg * 64 + wv * 16 + col;
        float sc = (Tg == 2) ? K2LOG2 : LOG2E;
        const float* r0 = Whh + g * 64 + q * 8;
        #pragma unroll
        for (int j = 0; j < 8; ++j) {
            w0[Tg][j] = (_Float16)(r0[j] * sc);
            w1[Tg][j] = (_Float16)(r0[32 + j] * sc);
            wx[Tg][j] = (q == 0) ? (_Float16)(Wih[g * 8 + j] * sc) : (_Float16)0.f;
        }
    }
}

// P[Tg] = x-contribution + bias (C-init). Issued in the ds-latency shadow.
__device__ __forceinline__ void pchain(half8 ax, const half8 wx[4],
                                       const f32x4 biasv[4], f32x4 P[4])
{
    P[2] = __builtin_amdgcn_mfma_f32_16x16x32_f16(ax, wx[2], biasv[2], 0, 0, 0);
    P[0] = __builtin_amdgcn_mfma_f32_16x16x32_f16(ax, wx[0], biasv[0], 0, 0, 0);
    P[1] = __builtin_amdgcn_mfma_f32_16x16x32_f16(ax, wx[1], biasv[1], 0, 0, 0);
    P[3] = __builtin_amdgcn_mfma_f32_16x16x32_f16(ax, wx[3], biasv[3], 0, 0, 0);
}

// Critical path: 8 MFMA (4 chains depth 2, gate order g,i,f,o) + cell update.
__device__ __forceinline__ float qcell(half8 a0, half8 a1,
    const half8 w0[4], const half8 w1[4], const f32x4 P[4], float& cS)
{
    f32x4 Qg = __builtin_amdgcn_mfma_f32_16x16x32_f16(a0, w0[2], P[2], 0, 0, 0);
    f32x4 Qi = __builtin_amdgcn_mfma_f32_16x16x32_f16(a0, w0[0], P[0], 0, 0, 0);
    f32x4 Qf = __builtin_amdgcn_mfma_f32_16x16x32_f16(a0, w0[1], P[1], 0, 0, 0);
    f32x4 Qo = __builtin_amdgcn_mfma_f32_16x16x32_f16(a0, w0[3], P[3], 0, 0, 0);
    Qg = __builtin_amdgcn_mfma_f32_16x16x32_f16(a1, w1[2], Qg, 0, 0, 0);
    Qi = __builtin_amdgcn_mfma_f32_16x16x32_f16(a1, w1[0], Qi, 0, 0, 0);
    Qf = __builtin_amdgcn_mfma_f32_16x16x32_f16(a1, w1[1], Qf, 0, 0, 0);
    Qo = __builtin_amdgcn_mfma_f32_16x16x32_f16(a1, w1[3], Qo, 0, 0, 0);
    float tg = tanh_pre(Qg[0]);        // Qg retires first
    float si = sig_pre(Qi[0]);
    float sf = sig_pre(Qf[0]);
    float so = sig_pre(Qo[0]);
    cS = sf * cS + (si * tg) * K2LOG2;
    return so * tanh_pre(cS);
}

__global__ __launch_bounds__(256, 1)
void seq2seq_v8(const float* __restrict__ x_seq,
                const float* __restrict__ eWih, const float* __restrict__ eWhh,
                const float* __restrict__ ebih, const float* __restrict__ ebhh,
                const float* __restrict__ dWih, const float* __restrict__ dWhh,
                const float* __restrict__ dbih, const float* __restrict__ dbhh,
                const float* __restrict__ fcW,  const float* __restrict__ fcb,
                float* __restrict__ out)
{
    __shared__ __align__(16) _Float16 xs[(Tt + 4) * XSTRIDE];  // 33 KB; predbuf alias later
    __shared__ __align__(16) _Float16 A0[ABUF];
    __shared__ __align__(16) _Float16 A1[ABUF];
    __shared__ float fcWT[Hh * 9 + 8];
    __shared__ float sfcb[Ff];
    __shared__ __align__(16) _Float16 xdec[MB * Ff];

    const int tid  = threadIdx.x;
    const int wv   = tid >> 6;
    const int lane = tid & 63;
    const int q    = lane >> 4;
    const int col  = lane & 15;
    const int u    = wv * 16 + col;
    const int b0   = blockIdx.x * MB;

    half8 w0[4], w1[4], wx[4];
    load_wfrags(eWhh, eWih, wv, q, col, w0, w1, wx);
    f32x4 biasv[4];
    #pragma unroll
    for (int Tg = 0; Tg < 4; ++Tg) {
        int g = Tg * 64 + u;
        float sc = (Tg == 2) ? K2LOG2 : LOG2E;
        float bv = (ebih[g] + ebhh[g]) * sc;
        biasv[Tg] = (f32x4){bv, bv, bv, bv};
    }

    // init: zero A buffers + xs pad rows, stage fc weights + x sequence (fp32 -> fp16)
    { int* Z0 = (int*)A0; int* Z1 = (int*)A1;
      for (int i = tid; i < ABUF / 2; i += 256) { Z0[i] = 0; Z1[i] = 0; } }
    for (int i = tid; i < Ff * Hh; i += 256) { int f = i >> 6, uu = i & 63; fcWT[uu * 9 + f] = fcW[i]; }
    if (tid < Ff) sfcb[tid] = fcb[tid];
    if (tid < 64) ((int*)xs)[Tt * 16 + tid] = 0;         // zero 4 pad rows
    for (int i = tid; i < MB * Tt * 2; i += 256) {       // 4096 float4s
        int b   = i >> 10;
        int rem = i & 1023;
        int t   = rem >> 1;
        int f4  = (rem & 1) * 4;
        const float* src = x_seq + ((size_t)(b0 + b) * Tt + t) * Ff + f4;
        half4 s = { (_Float16)src[0], (_Float16)src[1], (_Float16)src[2], (_Float16)src[3] };
        *(half4*)(&xs[t * XSTRIDE + b * 8 + f4]) = s;
    }
    __syncthreads();                                     // staging visible

    // per-lane hoisted pointers
    const _Float16* arA = A0 + arow_base(col) + q * 8;
    const _Float16* arB = A1 + arow_base(col) + q * 8;
    _Float16* hwA = A0 + 4 * q * ROWS + u;
    _Float16* hwB = A1 + 4 * q * ROWS + u;
    const _Float16* xq = xs + (col >> 2) * 8;            // x walker (broadcast groups)

    float cS = 0.f;
    f32x4 Pc[4], Pn[4];
    half8 xa;
    {   half8 x0 = *(const half8*)(xq);                  // x(0)
        pchain(x0, wx, biasv, Pc);                       // P for step 0
        xa = *(const half8*)(xq + XSTRIDE);              // x(1)
        xq += 2 * XSTRIDE; }

    // ============ encoder: 512 steps; P-chain issues in the ds-read shadow ============
    for (int t = 0; t < Tt; t += 2) {
        __syncthreads();                                 // h(t) visible (A0)
        {
            half8 a0 = *(const half8*)(arA);             // ds_reads issue first
            half8 a1 = *(const half8*)(arA + 32);
            pchain(xa, wx, biasv, Pn);                   // P(t+1): fills ds-latency window
            half8 xn = *(const half8*)(xq); xq += XSTRIDE;   // x(t+2), off-CP
            float hn = qcell(a0, a1, w0, w1, Pc, cS);
            *hwB = (_Float16)hn;                         // h(t+1) -> A1
            xa = xn;
        }
        __syncthreads();                                 // h(t+1) visible (A1)
        {
            half8 a0 = *(const half8*)(arB);
            half8 a1 = *(const half8*)(arB + 32);
            pchain(xa, wx, biasv, Pc);                   // P(t+2)
            half8 xn = *(const half8*)(xq); xq += XSTRIDE;   // x(t+3) (pad rows at end)
            float hn = qcell(a0, a1, w0, w1, Pn, cS);
            *hwA = (_Float16)hn;                         // h(t+2) -> A0
            xa = xn;
        }
    }
    // after loop: h(512) in A0.

    // ================= decoder setup =================
    load_wfrags(dWhh, dWih, wv, q, col, w0, w1, wx);
    #pragma unroll
    for (int Tg = 0; Tg < 4; ++Tg) {
        int g = Tg * 64 + u;
        float sc = (Tg == 2) ? K2LOG2 : LOG2E;
        float bv = (dbih[g] + dbhh[g]) * sc;
        biasv[Tg] = (f32x4){bv, bv, bv, bv};
    }
    if (tid < MB * Ff) xdec[tid] = xs[(Tt - 1) * XSTRIDE + tid];   // x_dec(0)=x[:,T-1]
    __syncthreads();                                     // h(512) + xdec visible

    float* predbuf = (float*)xs;                         // 8 KB alias over dead xs
    const _Float16* xdp = xdec + (col >> 2) * 8;

    // ============ decoder: 64 steps (A0 -> A1 -> ...), fc + feedback ============
    for (int p = 0; p < Pp; ++p) {
        const _Float16* ar = (p & 1) ? arB : arA;
        _Float16*       hw = (p & 1) ? hwA : hwB;
        const _Float16* hb = (p & 1) ? A0  : A1;         // buffer written this step
        half8 a0 = *(const half8*)(ar);
        half8 a1 = *(const half8*)(ar + 32);
        half8 ax = *(const half8*)(xdp);
        pchain(ax, wx, biasv, Pc);                       // fills ds window (xdec read above)
        float hn = qcell(a0, a1, w0, w1, Pc, cS);
        *hw = (_Float16)hn;
        __syncthreads();
        if (tid < MB * Ff) {
            int b = tid >> 3, f = tid & 7;
            const _Float16* hr = hb + (4 * b) * ROWS;
            float s = sfcb[f];
            #pragma unroll
            for (int ch = 0; ch < 8; ++ch) {
                half8 hh = *(const half8*)(hr + ch * 8);
                #pragma unroll
                for (int j = 0; j < 8; ++j)
                    s += (float)hh[j] * fcWT[(ch * 8 + j) * 9 + f];
            }
            predbuf[b * (Pp * Ff) + p * Ff + f] = s;
            xdec[tid] = (_Float16)s;
        }
        __syncthreads();
    }

    // ================= flush preds: LDS -> global, coalesced float4 =================
    {
        f32x4* out4 = (f32x4*)out + (size_t)b0 * (Pp * Ff / 4);
        const f32x4* pb4 = (const f32x4*)predbuf;
        for (int i = tid; i < MB * Pp * Ff / 4; i += 256)
            out4[i] = pb4[i];
    }
}

extern "C" void kernel_launch(void* const* d_in, const int* in_sizes, int n_in,
                              void* d_out, int out_size, void* d_ws, size_t ws_size,
                              hipStream_t stream) {
    (void)in_sizes; (void)n_in; (void)d_ws; (void)ws_size; (void)out_size;
    hipLaunchKernelGGL(seq2seq_v8, dim3(NBLK), dim3(256), 0, stream,
                       (const float*)d_in[0],
                       (const float*)d_in[1], (const float*)d_in[2],
                       (const float*)d_in[3], (const float*)d_in[4],
                       (const float*)d_in[5], (const float*)d_in[6],
                       (const float*)d_in[7], (const float*)d_in[8],
                       (const float*)d_in[9], (const float*)d_in[10],
                       (float*)d_out);
}